// Round 1
// baseline (618.247 us; speedup 1.0000x reference)
//
#include <hip/hip_runtime.h>
#include <hip/hip_bf16.h>

typedef __bf16 bf16;
typedef bf16 bf16x8 __attribute__((ext_vector_type(8)));
typedef float f32x4 __attribute__((ext_vector_type(4)));
typedef unsigned short ushortT;
typedef ushortT ushort8 __attribute__((ext_vector_type(8)));

#define DEV __device__ __forceinline__

constexpr int DMODEL = 1024;
constexpr int NH = 16;
constexpr int DK = 64;
constexpr int SEQ = 2048;
constexpr int BATCH = 4;
constexpr int MROWS = BATCH * SEQ;   // 8192
constexpr int KDIM = 1024;

#define GLOAD_LDS16(g, l) __builtin_amdgcn_global_load_lds( \
    (const __attribute__((address_space(1))) void*)(g), \
    (__attribute__((address_space(3))) void*)(l), 16, 0, 0)

// ---------------- f32 -> bf16 conversion ----------------
__global__ void cvt_bf16(const float* __restrict__ src, bf16* __restrict__ dst, int n) {
    int i = (blockIdx.x * blockDim.x + threadIdx.x) * 8;
    if (i >= n) return;
    float4 f0 = *reinterpret_cast<const float4*>(src + i);
    float4 f1 = *reinterpret_cast<const float4*>(src + i + 4);
    bf16x8 o;
    o[0] = (bf16)f0.x; o[1] = (bf16)f0.y; o[2] = (bf16)f0.z; o[3] = (bf16)f0.w;
    o[4] = (bf16)f1.x; o[5] = (bf16)f1.y; o[6] = (bf16)f1.z; o[7] = (bf16)f1.w;
    *reinterpret_cast<bf16x8*>(dst + i) = o;
}

// ---------------- RoPE tables ----------------
__global__ void rope_tab(float* __restrict__ cosT, float* __restrict__ sinT) {
    int i = blockIdx.x * blockDim.x + threadIdx.x;  // [0, 2048*32)
    int p = i >> 5, k = i & 31;
    float inv = powf(10000.0f, -2.0f * (float)k / 64.0f);
    float ang = (float)p * inv;
    cosT[i] = cosf(ang);
    sinT[i] = sinf(ang);
}

// ---------------- QKV GEMM (C = X * W^T), RoPE fused, out bf16 [B,H,S,DK] ----------------
__global__ __launch_bounds__(256) void gemm_qkv(
    const bf16* __restrict__ Xb,
    const bf16* __restrict__ Wqb, const bf16* __restrict__ Wkb, const bf16* __restrict__ Wvb,
    bf16* __restrict__ Qb, bf16* __restrict__ Kb, bf16* __restrict__ Vb,
    const int* __restrict__ tokpos, const float* __restrict__ cosT, const float* __restrict__ sinT)
{
    __shared__ bf16 As[128 * 64];
    __shared__ bf16 Bs[128 * 64];

    const int which = blockIdx.z;
    const bf16* Bmat = which == 0 ? Wqb : (which == 1 ? Wkb : Wvb);
    bf16* Out = which == 0 ? Qb : (which == 1 ? Kb : Vb);

    const int m0 = blockIdx.x * 128;
    const int n0 = blockIdx.y * 128;
    const int t = threadIdx.x;
    const int w = t >> 6, l = t & 63;
    const int wr = w >> 1, wc = w & 1;
    const int lrow = l >> 3;          // 0..7
    const int lcol = (l & 7) * 8;     // bf16 col within BK
    const int lm = l & 15, lg = l >> 4;

    f32x4 acc[4][4] = {};

    for (int kt = 0; kt < KDIM; kt += 64) {
#pragma unroll
        for (int c = 0; c < 4; ++c) {
            int ci = c * 4 + w;            // 0..15
            int row = ci * 8 + lrow;       // 0..127
            const bf16* ga = Xb + (size_t)(m0 + row) * KDIM + kt + lcol;
            const bf16* gb = Bmat + (size_t)(n0 + row) * KDIM + kt + lcol;
            GLOAD_LDS16(ga, As + ci * 512);
            GLOAD_LDS16(gb, Bs + ci * 512);
        }
        __syncthreads();
#pragma unroll
        for (int kk = 0; kk < 2; ++kk) {
            bf16x8 af[4], bfr[4];
#pragma unroll
            for (int mi = 0; mi < 4; ++mi)
                af[mi] = *reinterpret_cast<const bf16x8*>(As + (wr * 64 + mi * 16 + lm) * 64 + kk * 32 + lg * 8);
#pragma unroll
            for (int ni = 0; ni < 4; ++ni)
                bfr[ni] = *reinterpret_cast<const bf16x8*>(Bs + (wc * 64 + ni * 16 + lm) * 64 + kk * 32 + lg * 8);
#pragma unroll
            for (int mi = 0; mi < 4; ++mi)
#pragma unroll
                for (int ni = 0; ni < 4; ++ni)
                    acc[mi][ni] = __builtin_amdgcn_mfma_f32_16x16x32_bf16(af[mi], bfr[ni], acc[mi][ni], 0, 0, 0);
        }
        __syncthreads();
    }

    // epilogue: RoPE (Q,K only) + scatter to [B,H,S,DK] bf16
#pragma unroll
    for (int ni = 0; ni < 4; ++ni) {
        int j = n0 + wc * 64 + ni * 16 + lm;   // global col in [0,1024)
        int h = j >> 6, d = j & 63;
        int k2 = d >> 1;
        bool even = (d & 1) == 0;
#pragma unroll
        for (int mi = 0; mi < 4; ++mi) {
#pragma unroll
            for (int r = 0; r < 4; ++r) {
                int rowg = m0 + wr * 64 + mi * 16 + lg * 4 + r;   // global row
                float v = acc[mi][ni][r];
                float outv;
                if (which < 2) {
                    int p = tokpos[rowg];
                    float cv = cosT[p * 32 + k2];
                    float sv = sinT[p * 32 + k2];
                    float u = __shfl_xor(v, 1);
                    outv = even ? (v * cv - u * sv) : (v * cv + u * sv);
                } else {
                    outv = v;
                }
                int bb = rowg >> 11, ss = rowg & 2047;
                size_t oidx = (((size_t)(bb * NH + h)) * SEQ + ss) * DK + d;
                Out[oidx] = (bf16)outv;
            }
        }
    }
}

// ---------------- V transpose [B,H,S,DK] -> [B,H,DK,S] ----------------
__global__ void vtrans(const bf16* __restrict__ Vb, bf16* __restrict__ Vt) {
    __shared__ ushortT tile[64][66];
    int bh = blockIdx.y, st = blockIdx.x;
    int t = threadIdx.x;
    int r = t >> 2, c4 = (t & 3) * 16;
    const ushortT* src = (const ushortT*)(Vb + ((size_t)bh * SEQ + st * 64 + r) * DK + c4);
    *reinterpret_cast<ushort8*>(&tile[r][c4]) = *reinterpret_cast<const ushort8*>(src);
    *reinterpret_cast<ushort8*>(&tile[r][c4 + 8]) = *reinterpret_cast<const ushort8*>(src + 8);
    __syncthreads();
    ushort8 o0, o1;
#pragma unroll
    for (int i = 0; i < 8; ++i) o0[i] = tile[c4 + i][r];
#pragma unroll
    for (int i = 0; i < 8; ++i) o1[i] = tile[c4 + 8 + i][r];
    ushortT* dst = (ushortT*)(Vt + ((size_t)bh * DK + r) * SEQ + st * 64 + c4);
    *reinterpret_cast<ushort8*>(dst) = o0;
    *reinterpret_cast<ushort8*>(dst + 8) = o1;
}

// ---------------- flash attention (causal) ----------------
// grid: (S/64, B*H); block 256 = 4 waves, each wave owns 16 q-rows.
__global__ __launch_bounds__(256) void attn(
    const bf16* __restrict__ Qb, const bf16* __restrict__ Kb, const bf16* __restrict__ Vt,
    bf16* __restrict__ Ab)
{
    __shared__ bf16 Plds[4][16 * 32];
    const int bh = blockIdx.y;
    const int qt = blockIdx.x;
    const int t = threadIdx.x, w = t >> 6, l = t & 63;
    const int lm = l & 15, lg = l >> 4;
    const int q0 = qt * 64 + w * 16;            // this wave's first q-row (within seq)
    const bf16* Qh = Qb + (size_t)bh * SEQ * DK;
    const bf16* Kh = Kb + (size_t)bh * SEQ * DK;
    const bf16* Vh = Vt + (size_t)bh * DK * SEQ;

    bf16x8 qf[2];
#pragma unroll
    for (int kk = 0; kk < 2; ++kk)
        qf[kk] = *reinterpret_cast<const bf16x8*>(Qh + (size_t)(q0 + lm) * DK + kk * 32 + lg * 8);

    f32x4 o[4] = {};
    float mrow[4], lsum[4];
#pragma unroll
    for (int i = 0; i < 4; ++i) { mrow[i] = -1e30f; lsum[i] = 0.0f; }

    const int kv_end = q0 + 16;   // exclusive causal bound for this wave
    for (int kv0 = 0; kv0 < kv_end; kv0 += 32) {
        f32x4 s[2] = {};
#pragma unroll
        for (int c = 0; c < 2; ++c) {
#pragma unroll
            for (int kk = 0; kk < 2; ++kk) {
                bf16x8 kf = *reinterpret_cast<const bf16x8*>(Kh + (size_t)(kv0 + c * 16 + lm) * DK + kk * 32 + lg * 8);
                s[c] = __builtin_amdgcn_mfma_f32_16x16x32_bf16(qf[kk], kf, s[c], 0, 0, 0);
            }
        }
        float p[2][4];
#pragma unroll
        for (int i = 0; i < 4; ++i) {
            int qrow = q0 + lg * 4 + i;
            float s0 = s[0][i] * 0.125f;
            float s1 = s[1][i] * 0.125f;
            if (kv0 + lm > qrow)      s0 = -1e30f;
            if (kv0 + 16 + lm > qrow) s1 = -1e30f;
            p[0][i] = s0; p[1][i] = s1;
            float mx = fmaxf(s0, s1);
#pragma unroll
            for (int d = 1; d < 16; d <<= 1) mx = fmaxf(mx, __shfl_xor(mx, d));
            float mnew = fmaxf(mrow[i], mx);
            float alpha = __expf(mrow[i] - mnew);
            mrow[i] = mnew;
            float p0 = __expf(s0 - mnew);
            float p1 = __expf(s1 - mnew);
            p[0][i] = p0; p[1][i] = p1;
            float ps = p0 + p1;
#pragma unroll
            for (int d = 1; d < 16; d <<= 1) ps += __shfl_xor(ps, d);
            lsum[i] = lsum[i] * alpha + ps;
#pragma unroll
            for (int dc = 0; dc < 4; ++dc) o[dc][i] *= alpha;
        }
        // P -> LDS (C-layout) -> A-frag layout
#pragma unroll
        for (int c = 0; c < 2; ++c)
#pragma unroll
            for (int i = 0; i < 4; ++i)
                Plds[w][(lg * 4 + i) * 32 + c * 16 + lm] = (bf16)p[c][i];
        bf16x8 pf = *reinterpret_cast<const bf16x8*>(&Plds[w][lm * 32 + lg * 8]);
#pragma unroll
        for (int dc = 0; dc < 4; ++dc) {
            bf16x8 vf = *reinterpret_cast<const bf16x8*>(Vh + (size_t)(dc * 16 + lm) * SEQ + kv0 + lg * 8);
            o[dc] = __builtin_amdgcn_mfma_f32_16x16x32_bf16(pf, vf, o[dc], 0, 0, 0);
        }
    }

    const int b = bh >> 4, h = bh & 15;
#pragma unroll
    for (int dc = 0; dc < 4; ++dc) {
#pragma unroll
        for (int i = 0; i < 4; ++i) {
            int qrow = q0 + lg * 4 + i;
            float ov = o[dc][i] / lsum[i];
            Ab[((size_t)(b * SEQ + qrow)) * DMODEL + h * 64 + dc * 16 + lm] = (bf16)ov;
        }
    }
}

// ---------------- output GEMM (d_out = Ab * Wo^T), f32 out ----------------
__global__ __launch_bounds__(256) void gemm_out(
    const bf16* __restrict__ Ab, const bf16* __restrict__ Wob, float* __restrict__ Out)
{
    __shared__ bf16 As[128 * 64];
    __shared__ bf16 Bs[128 * 64];

    const int m0 = blockIdx.x * 128;
    const int n0 = blockIdx.y * 128;
    const int t = threadIdx.x;
    const int w = t >> 6, l = t & 63;
    const int wr = w >> 1, wc = w & 1;
    const int lrow = l >> 3;
    const int lcol = (l & 7) * 8;
    const int lm = l & 15, lg = l >> 4;

    f32x4 acc[4][4] = {};

    for (int kt = 0; kt < KDIM; kt += 64) {
#pragma unroll
        for (int c = 0; c < 4; ++c) {
            int ci = c * 4 + w;
            int row = ci * 8 + lrow;
            const bf16* ga = Ab + (size_t)(m0 + row) * KDIM + kt + lcol;
            const bf16* gb = Wob + (size_t)(n0 + row) * KDIM + kt + lcol;
            GLOAD_LDS16(ga, As + ci * 512);
            GLOAD_LDS16(gb, Bs + ci * 512);
        }
        __syncthreads();
#pragma unroll
        for (int kk = 0; kk < 2; ++kk) {
            bf16x8 af[4], bfr[4];
#pragma unroll
            for (int mi = 0; mi < 4; ++mi)
                af[mi] = *reinterpret_cast<const bf16x8*>(As + (wr * 64 + mi * 16 + lm) * 64 + kk * 32 + lg * 8);
#pragma unroll
            for (int ni = 0; ni < 4; ++ni)
                bfr[ni] = *reinterpret_cast<const bf16x8*>(Bs + (wc * 64 + ni * 16 + lm) * 64 + kk * 32 + lg * 8);
#pragma unroll
            for (int mi = 0; mi < 4; ++mi)
#pragma unroll
                for (int ni = 0; ni < 4; ++ni)
                    acc[mi][ni] = __builtin_amdgcn_mfma_f32_16x16x32_bf16(af[mi], bfr[ni], acc[mi][ni], 0, 0, 0);
        }
        __syncthreads();
    }

#pragma unroll
    for (int ni = 0; ni < 4; ++ni) {
        int j = n0 + wc * 64 + ni * 16 + lm;
#pragma unroll
        for (int mi = 0; mi < 4; ++mi) {
#pragma unroll
            for (int r = 0; r < 4; ++r) {
                int rowg = m0 + wr * 64 + mi * 16 + lg * 4 + r;
                Out[(size_t)rowg * DMODEL + j] = acc[mi][ni][r];
            }
        }
    }
}

// ---------------- launch ----------------
extern "C" void kernel_launch(void* const* d_in, const int* in_sizes, int n_in,
                              void* d_out, int out_size, void* d_ws, size_t ws_size,
                              hipStream_t stream) {
    const float* X  = (const float*)d_in[0];
    const int* tokpos = (const int*)d_in[1];
    const float* Wq = (const float*)d_in[2];
    const float* Wk = (const float*)d_in[3];
    const float* Wv = (const float*)d_in[4];
    const float* Wo = (const float*)d_in[5];

    char* ws = (char*)d_ws;
    bf16* Xb  = (bf16*)(ws + 0);            // 16 MB
    bf16* Wqb = (bf16*)(ws + 16777216);     // 2 MB
    bf16* Wkb = (bf16*)(ws + 18874368);
    bf16* Wvb = (bf16*)(ws + 20971520);
    bf16* Wob = (bf16*)(ws + 23068672);
    float* cosT = (float*)(ws + 25165824);  // 256 KB
    float* sinT = (float*)(ws + 25427968);
    bf16* Qb = (bf16*)(ws + 25690112);      // 16 MB
    bf16* Kb = (bf16*)(ws + 42467328);
    bf16* Vb = (bf16*)(ws + 59244544);
    bf16* Vt = (bf16*)(ws + 76021760);
    bf16* Ab = (bf16*)(ws + 92798976);      // ends at 109,576,192

    cvt_bf16<<<4096, 256, 0, stream>>>(X, Xb, MROWS * DMODEL);
    cvt_bf16<<<512, 256, 0, stream>>>(Wq, Wqb, DMODEL * DMODEL);
    cvt_bf16<<<512, 256, 0, stream>>>(Wk, Wkb, DMODEL * DMODEL);
    cvt_bf16<<<512, 256, 0, stream>>>(Wv, Wvb, DMODEL * DMODEL);
    cvt_bf16<<<512, 256, 0, stream>>>(Wo, Wob, DMODEL * DMODEL);
    rope_tab<<<256, 256, 0, stream>>>(cosT, sinT);

    gemm_qkv<<<dim3(MROWS / 128, DMODEL / 128, 3), 256, 0, stream>>>(
        Xb, Wqb, Wkb, Wvb, Qb, Kb, Vb, tokpos, cosT, sinT);

    vtrans<<<dim3(SEQ / 64, BATCH * NH), 256, 0, stream>>>(Vb, Vt);

    attn<<<dim3(SEQ / 64, BATCH * NH), 256, 0, stream>>>(Qb, Kb, Vt, Ab);

    gemm_out<<<dim3(MROWS / 128, DMODEL / 128), 256, 0, stream>>>(Ab, Wob, (float*)d_out);
}

// Round 2
// 352.495 us; speedup vs baseline: 1.7539x; 1.7539x over previous
//
#include <hip/hip_runtime.h>
#include <hip/hip_bf16.h>

typedef __bf16 bf16;
typedef bf16 bf16x8 __attribute__((ext_vector_type(8)));
typedef float f32x4 __attribute__((ext_vector_type(4)));
typedef unsigned short ushortT;
typedef ushortT ushort8 __attribute__((ext_vector_type(8)));

#define DEV __device__ __forceinline__

constexpr int DMODEL = 1024;
constexpr int NH = 16;
constexpr int DK = 64;
constexpr int SEQ = 2048;
constexpr int BATCH = 4;
constexpr int MROWS = BATCH * SEQ;   // 8192
constexpr int KDIM = 1024;

#define GLOAD_LDS16(g, l) __builtin_amdgcn_global_load_lds( \
    (const __attribute__((address_space(1))) void*)(g), \
    (__attribute__((address_space(3))) void*)(l), 16, 0, 0)

// ---------------- f32 -> bf16 conversion ----------------
__global__ void cvt_bf16(const float* __restrict__ src, bf16* __restrict__ dst, int n) {
    int i = (blockIdx.x * blockDim.x + threadIdx.x) * 8;
    if (i >= n) return;
    float4 f0 = *reinterpret_cast<const float4*>(src + i);
    float4 f1 = *reinterpret_cast<const float4*>(src + i + 4);
    bf16x8 o;
    o[0] = (bf16)f0.x; o[1] = (bf16)f0.y; o[2] = (bf16)f0.z; o[3] = (bf16)f0.w;
    o[4] = (bf16)f1.x; o[5] = (bf16)f1.y; o[6] = (bf16)f1.z; o[7] = (bf16)f1.w;
    *reinterpret_cast<bf16x8*>(dst + i) = o;
}

// ---------------- RoPE tables ----------------
__global__ void rope_tab(float* __restrict__ cosT, float* __restrict__ sinT) {
    int i = blockIdx.x * blockDim.x + threadIdx.x;  // [0, 2048*32)
    int p = i >> 5, k = i & 31;
    float inv = powf(10000.0f, -2.0f * (float)k / 64.0f);
    float ang = (float)p * inv;
    cosT[i] = cosf(ang);
    sinT[i] = sinf(ang);
}

// ---------------- QKV GEMM (C = X * W^T), RoPE fused, out bf16 [B,H,S,DK] ----------------
__global__ __launch_bounds__(256) void gemm_qkv(
    const bf16* __restrict__ Xb,
    const bf16* __restrict__ Wqb, const bf16* __restrict__ Wkb, const bf16* __restrict__ Wvb,
    bf16* __restrict__ Qb, bf16* __restrict__ Kb, bf16* __restrict__ Vb,
    const int* __restrict__ tokpos, const float* __restrict__ cosT, const float* __restrict__ sinT)
{
    __shared__ bf16 As[128 * 64];
    __shared__ bf16 Bs[128 * 64];

    const int which = blockIdx.z;
    const bf16* Bmat = which == 0 ? Wqb : (which == 1 ? Wkb : Wvb);
    bf16* Out = which == 0 ? Qb : (which == 1 ? Kb : Vb);

    const int m0 = blockIdx.x * 128;
    const int n0 = blockIdx.y * 128;
    const int t = threadIdx.x;
    const int w = t >> 6, l = t & 63;
    const int wr = w >> 1, wc = w & 1;
    const int lrow = l >> 3;          // 0..7
    const int lcol = (l & 7) * 8;     // bf16 col within BK
    const int lm = l & 15, lg = l >> 4;

    f32x4 acc[4][4] = {};

    for (int kt = 0; kt < KDIM; kt += 64) {
#pragma unroll
        for (int c = 0; c < 4; ++c) {
            int ci = c * 4 + w;            // 0..15
            int row = ci * 8 + lrow;       // 0..127
            const bf16* ga = Xb + (size_t)(m0 + row) * KDIM + kt + lcol;
            const bf16* gb = Bmat + (size_t)(n0 + row) * KDIM + kt + lcol;
            GLOAD_LDS16(ga, As + ci * 512);
            GLOAD_LDS16(gb, Bs + ci * 512);
        }
        __syncthreads();
#pragma unroll
        for (int kk = 0; kk < 2; ++kk) {
            bf16x8 af[4], bfr[4];
#pragma unroll
            for (int mi = 0; mi < 4; ++mi)
                af[mi] = *reinterpret_cast<const bf16x8*>(As + (wr * 64 + mi * 16 + lm) * 64 + kk * 32 + lg * 8);
#pragma unroll
            for (int ni = 0; ni < 4; ++ni)
                bfr[ni] = *reinterpret_cast<const bf16x8*>(Bs + (wc * 64 + ni * 16 + lm) * 64 + kk * 32 + lg * 8);
#pragma unroll
            for (int mi = 0; mi < 4; ++mi)
#pragma unroll
                for (int ni = 0; ni < 4; ++ni)
                    acc[mi][ni] = __builtin_amdgcn_mfma_f32_16x16x32_bf16(af[mi], bfr[ni], acc[mi][ni], 0, 0, 0);
        }
        __syncthreads();
    }

    // epilogue: RoPE (Q,K only) + scatter to [B,H,S,DK] bf16
#pragma unroll
    for (int ni = 0; ni < 4; ++ni) {
        int j = n0 + wc * 64 + ni * 16 + lm;   // global col in [0,1024)
        int h = j >> 6, d = j & 63;
        int k2 = d >> 1;
        bool even = (d & 1) == 0;
#pragma unroll
        for (int mi = 0; mi < 4; ++mi) {
#pragma unroll
            for (int r = 0; r < 4; ++r) {
                int rowg = m0 + wr * 64 + mi * 16 + lg * 4 + r;   // global row
                float v = acc[mi][ni][r];
                float outv;
                if (which < 2) {
                    int p = tokpos[rowg];
                    float cv = cosT[p * 32 + k2];
                    float sv = sinT[p * 32 + k2];
                    float u = __shfl_xor(v, 1);
                    outv = even ? (v * cv - u * sv) : (v * cv + u * sv);
                } else {
                    outv = v;
                }
                int bb = rowg >> 11, ss = rowg & 2047;
                size_t oidx = (((size_t)(bb * NH + h)) * SEQ + ss) * DK + d;
                Out[oidx] = (bf16)outv;
            }
        }
    }
}

// ---------------- V transpose [B,H,S,DK] -> [B,H,DK,S] ----------------
__global__ void vtrans(const bf16* __restrict__ Vb, bf16* __restrict__ Vt) {
    __shared__ ushortT tile[64][66];
    int bh = blockIdx.y, st = blockIdx.x;
    int t = threadIdx.x;
    int r = t >> 2, c4 = (t & 3) * 16;
    const ushortT* src = (const ushortT*)(Vb + ((size_t)bh * SEQ + st * 64 + r) * DK + c4);
    *reinterpret_cast<ushort8*>(&tile[r][c4]) = *reinterpret_cast<const ushort8*>(src);
    *reinterpret_cast<ushort8*>(&tile[r][c4 + 8]) = *reinterpret_cast<const ushort8*>(src + 8);
    __syncthreads();
    ushort8 o0, o1;
#pragma unroll
    for (int i = 0; i < 8; ++i) o0[i] = tile[c4 + i][r];
#pragma unroll
    for (int i = 0; i < 8; ++i) o1[i] = tile[c4 + 8 + i][r];
    ushortT* dst = (ushortT*)(Vt + ((size_t)bh * DK + r) * SEQ + st * 64 + c4);
    *reinterpret_cast<ushort8*>(dst) = o0;
    *reinterpret_cast<ushort8*>(dst + 8) = o1;
}

// ---------------- flash attention (causal), restructured ----------------
// grid: (B*H, S/128); block 256 = 4 waves, each wave owns 32 q-rows, KV tile 64.
constexpr float CL = 0.18033688011112042f;  // 0.125 * log2(e)

template<bool MASK>
DEV void attn_iter(int kv0, int q0, int lm, int lg,
                   const bf16* __restrict__ Kh, const bf16* __restrict__ Vh,
                   char* Pbase, const bf16x8 qf[2][2], const bf16x8& onesf,
                   f32x4 o[2][4], f32x4 osum[2], float mrow[2][4])
{
    f32x4 s[2][4] = {};
#pragma unroll
    for (int c = 0; c < 4; ++c) {
        bf16x8 kf0 = *reinterpret_cast<const bf16x8*>(Kh + (size_t)(kv0 + c * 16 + lm) * DK + lg * 8);
        bf16x8 kf1 = *reinterpret_cast<const bf16x8*>(Kh + (size_t)(kv0 + c * 16 + lm) * DK + 32 + lg * 8);
#pragma unroll
        for (int qi = 0; qi < 2; ++qi) {
            s[qi][c] = __builtin_amdgcn_mfma_f32_16x16x32_bf16(qf[qi][0], kf0, s[qi][c], 0, 0, 0);
            s[qi][c] = __builtin_amdgcn_mfma_f32_16x16x32_bf16(qf[qi][1], kf1, s[qi][c], 0, 0, 0);
        }
    }
    // softmax (p overwrites s), alpha-rescale o/osum, store P to swizzled LDS
#pragma unroll
    for (int qi = 0; qi < 2; ++qi) {
#pragma unroll
        for (int i = 0; i < 4; ++i) {
            const int qrow = q0 + qi * 16 + lg * 4 + i;
            if (MASK) {
#pragma unroll
                for (int c = 0; c < 4; ++c)
                    if (kv0 + c * 16 + lm > qrow) s[qi][c][i] = -1e30f;
            }
            float mx = fmaxf(fmaxf(s[qi][0][i], s[qi][1][i]), fmaxf(s[qi][2][i], s[qi][3][i]));
            mx = fmaxf(mx, __shfl_xor(mx, 1));
            mx = fmaxf(mx, __shfl_xor(mx, 2));
            mx = fmaxf(mx, __shfl_xor(mx, 4));
            mx = fmaxf(mx, __shfl_xor(mx, 8));
            const float mnew = fmaxf(mrow[qi][i], mx);
            const float alpha = exp2f((mrow[qi][i] - mnew) * CL);
            mrow[qi][i] = mnew;
#pragma unroll
            for (int c = 0; c < 4; ++c)
                s[qi][c][i] = exp2f((s[qi][c][i] - mnew) * CL);
#pragma unroll
            for (int dc = 0; dc < 4; ++dc) o[qi][dc][i] *= alpha;
            osum[qi][i] *= alpha;
        }
        // store P (C-layout -> LDS, XOR-swizzled 16B slots within each 128B row)
#pragma unroll
        for (int i = 0; i < 4; ++i) {
            const int row = qi * 16 + lg * 4 + i;
            const int sw = (row & 7) << 4;
#pragma unroll
            for (int c = 0; c < 4; ++c)
                *reinterpret_cast<bf16*>(Pbase + row * 128 + (((c * 16 + lm) * 2) ^ sw)) = (bf16)s[qi][c][i];
        }
    }
    // PV: read P back as A-frags, V as B-frags; osum via ones-MFMA
    bf16x8 vf0[4], vf1[4];
#pragma unroll
    for (int dc = 0; dc < 4; ++dc) {
        vf0[dc] = *reinterpret_cast<const bf16x8*>(Vh + (size_t)(dc * 16 + lm) * SEQ + kv0 + lg * 8);
        vf1[dc] = *reinterpret_cast<const bf16x8*>(Vh + (size_t)(dc * 16 + lm) * SEQ + kv0 + 32 + lg * 8);
    }
#pragma unroll
    for (int qi = 0; qi < 2; ++qi) {
        const int row = qi * 16 + lm;
        const int sw = (row & 7) << 4;
        bf16x8 pf0 = *reinterpret_cast<const bf16x8*>(Pbase + row * 128 + ((lg * 16) ^ sw));
        bf16x8 pf1 = *reinterpret_cast<const bf16x8*>(Pbase + row * 128 + ((64 + lg * 16) ^ sw));
#pragma unroll
        for (int dc = 0; dc < 4; ++dc) {
            o[qi][dc] = __builtin_amdgcn_mfma_f32_16x16x32_bf16(pf0, vf0[dc], o[qi][dc], 0, 0, 0);
            o[qi][dc] = __builtin_amdgcn_mfma_f32_16x16x32_bf16(pf1, vf1[dc], o[qi][dc], 0, 0, 0);
        }
        osum[qi] = __builtin_amdgcn_mfma_f32_16x16x32_bf16(pf0, onesf, osum[qi], 0, 0, 0);
        osum[qi] = __builtin_amdgcn_mfma_f32_16x16x32_bf16(pf1, onesf, osum[qi], 0, 0, 0);
    }
}

__global__ __launch_bounds__(256) void attn(
    const bf16* __restrict__ Qb, const bf16* __restrict__ Kb, const bf16* __restrict__ Vt,
    bf16* __restrict__ Ab)
{
    __shared__ bf16 Plds[4 * 2048];   // 4 waves x 32x64 bf16 (4KB each)
    const int bh = blockIdx.x;
    const int qt = (int)gridDim.y - 1 - (int)blockIdx.y;   // longest tiles launch first
    const int t = threadIdx.x, w = t >> 6, l = t & 63;
    const int lm = l & 15, lg = l >> 4;
    const int q0 = qt * 128 + w * 32;
    const bf16* Qh = Qb + (size_t)bh * SEQ * DK;
    const bf16* Kh = Kb + (size_t)bh * SEQ * DK;
    const bf16* Vh = Vt + (size_t)bh * DK * SEQ;
    char* Pbase = reinterpret_cast<char*>(Plds) + w * 4096;

    bf16x8 qf[2][2];
#pragma unroll
    for (int qi = 0; qi < 2; ++qi)
#pragma unroll
        for (int kk = 0; kk < 2; ++kk)
            qf[qi][kk] = *reinterpret_cast<const bf16x8*>(Qh + (size_t)(q0 + qi * 16 + lm) * DK + kk * 32 + lg * 8);

    bf16x8 onesf;
#pragma unroll
    for (int j = 0; j < 8; ++j) onesf[j] = (bf16)1.0f;

    f32x4 o[2][4] = {};
    f32x4 osum[2] = {};
    float mrow[2][4];
#pragma unroll
    for (int qi = 0; qi < 2; ++qi)
#pragma unroll
        for (int i = 0; i < 4; ++i) mrow[qi][i] = -1e30f;

    const int nfull = q0 >> 6;
    int kv0 = 0;
    for (int tt = 0; tt < nfull; ++tt, kv0 += 64)
        attn_iter<false>(kv0, q0, lm, lg, Kh, Vh, Pbase, qf, onesf, o, osum, mrow);
    attn_iter<true>(kv0, q0, lm, lg, Kh, Vh, Pbase, qf, onesf, o, osum, mrow);

    const int b = bh >> 4, h = bh & 15;
    float rinv[2][4];
#pragma unroll
    for (int qi = 0; qi < 2; ++qi)
#pragma unroll
        for (int i = 0; i < 4; ++i) rinv[qi][i] = 1.0f / osum[qi][i];
#pragma unroll
    for (int qi = 0; qi < 2; ++qi)
#pragma unroll
        for (int dc = 0; dc < 4; ++dc)
#pragma unroll
            for (int i = 0; i < 4; ++i) {
                const int qrow = q0 + qi * 16 + lg * 4 + i;
                Ab[((size_t)(b * SEQ + qrow)) * DMODEL + h * 64 + dc * 16 + lm] =
                    (bf16)(o[qi][dc][i] * rinv[qi][i]);
            }
}

// ---------------- output GEMM (d_out = Ab * Wo^T), f32 out ----------------
__global__ __launch_bounds__(256) void gemm_out(
    const bf16* __restrict__ Ab, const bf16* __restrict__ Wob, float* __restrict__ Out)
{
    __shared__ bf16 As[128 * 64];
    __shared__ bf16 Bs[128 * 64];

    const int m0 = blockIdx.x * 128;
    const int n0 = blockIdx.y * 128;
    const int t = threadIdx.x;
    const int w = t >> 6, l = t & 63;
    const int wr = w >> 1, wc = w & 1;
    const int lrow = l >> 3;
    const int lcol = (l & 7) * 8;
    const int lm = l & 15, lg = l >> 4;

    f32x4 acc[4][4] = {};

    for (int kt = 0; kt < KDIM; kt += 64) {
#pragma unroll
        for (int c = 0; c < 4; ++c) {
            int ci = c * 4 + w;
            int row = ci * 8 + lrow;
            const bf16* ga = Ab + (size_t)(m0 + row) * KDIM + kt + lcol;
            const bf16* gb = Wob + (size_t)(n0 + row) * KDIM + kt + lcol;
            GLOAD_LDS16(ga, As + ci * 512);
            GLOAD_LDS16(gb, Bs + ci * 512);
        }
        __syncthreads();
#pragma unroll
        for (int kk = 0; kk < 2; ++kk) {
            bf16x8 af[4], bfr[4];
#pragma unroll
            for (int mi = 0; mi < 4; ++mi)
                af[mi] = *reinterpret_cast<const bf16x8*>(As + (wr * 64 + mi * 16 + lm) * 64 + kk * 32 + lg * 8);
#pragma unroll
            for (int ni = 0; ni < 4; ++ni)
                bfr[ni] = *reinterpret_cast<const bf16x8*>(Bs + (wc * 64 + ni * 16 + lm) * 64 + kk * 32 + lg * 8);
#pragma unroll
            for (int mi = 0; mi < 4; ++mi)
#pragma unroll
                for (int ni = 0; ni < 4; ++ni)
                    acc[mi][ni] = __builtin_amdgcn_mfma_f32_16x16x32_bf16(af[mi], bfr[ni], acc[mi][ni], 0, 0, 0);
        }
        __syncthreads();
    }

#pragma unroll
    for (int ni = 0; ni < 4; ++ni) {
        int j = n0 + wc * 64 + ni * 16 + lm;
#pragma unroll
        for (int mi = 0; mi < 4; ++mi) {
#pragma unroll
            for (int r = 0; r < 4; ++r) {
                int rowg = m0 + wr * 64 + mi * 16 + lg * 4 + r;
                Out[(size_t)rowg * DMODEL + j] = acc[mi][ni][r];
            }
        }
    }
}

// ---------------- launch ----------------
extern "C" void kernel_launch(void* const* d_in, const int* in_sizes, int n_in,
                              void* d_out, int out_size, void* d_ws, size_t ws_size,
                              hipStream_t stream) {
    const float* X  = (const float*)d_in[0];
    const int* tokpos = (const int*)d_in[1];
    const float* Wq = (const float*)d_in[2];
    const float* Wk = (const float*)d_in[3];
    const float* Wv = (const float*)d_in[4];
    const float* Wo = (const float*)d_in[5];

    char* ws = (char*)d_ws;
    bf16* Xb  = (bf16*)(ws + 0);            // 16 MB
    bf16* Wqb = (bf16*)(ws + 16777216);     // 2 MB
    bf16* Wkb = (bf16*)(ws + 18874368);
    bf16* Wvb = (bf16*)(ws + 20971520);
    bf16* Wob = (bf16*)(ws + 23068672);
    float* cosT = (float*)(ws + 25165824);  // 256 KB
    float* sinT = (float*)(ws + 25427968);
    bf16* Qb = (bf16*)(ws + 25690112);      // 16 MB
    bf16* Kb = (bf16*)(ws + 42467328);
    bf16* Vb = (bf16*)(ws + 59244544);
    bf16* Vt = (bf16*)(ws + 76021760);
    bf16* Ab = (bf16*)(ws + 92798976);      // ends at 109,576,192

    cvt_bf16<<<4096, 256, 0, stream>>>(X, Xb, MROWS * DMODEL);
    cvt_bf16<<<512, 256, 0, stream>>>(Wq, Wqb, DMODEL * DMODEL);
    cvt_bf16<<<512, 256, 0, stream>>>(Wk, Wkb, DMODEL * DMODEL);
    cvt_bf16<<<512, 256, 0, stream>>>(Wv, Wvb, DMODEL * DMODEL);
    cvt_bf16<<<512, 256, 0, stream>>>(Wo, Wob, DMODEL * DMODEL);
    rope_tab<<<256, 256, 0, stream>>>(cosT, sinT);

    gemm_qkv<<<dim3(MROWS / 128, DMODEL / 128, 3), 256, 0, stream>>>(
        Xb, Wqb, Wkb, Wvb, Qb, Kb, Vb, tokpos, cosT, sinT);

    vtrans<<<dim3(SEQ / 64, BATCH * NH), 256, 0, stream>>>(Vb, Vt);

    attn<<<dim3(BATCH * NH, SEQ / 128), 256, 0, stream>>>(Qb, Kb, Vt, Ab);

    gemm_out<<<dim3(MROWS / 128, DMODEL / 128), 256, 0, stream>>>(Ab, Wob, (float*)d_out);
}

// Round 3
// 326.280 us; speedup vs baseline: 1.8948x; 1.0803x over previous
//
#include <hip/hip_runtime.h>
#include <hip/hip_bf16.h>

typedef __bf16 bf16;
typedef bf16 bf16x8 __attribute__((ext_vector_type(8)));
typedef bf16 bf16x4 __attribute__((ext_vector_type(4)));
typedef float f32x4 __attribute__((ext_vector_type(4)));
typedef unsigned int uintT;
typedef uintT uint4v __attribute__((ext_vector_type(4)));
typedef unsigned short ushortT;
typedef ushortT ushort8 __attribute__((ext_vector_type(8)));

#define DEV __device__ __forceinline__

constexpr int DMODEL = 1024;
constexpr int NH = 16;
constexpr int DK = 64;
constexpr int SEQ = 2048;
constexpr int BATCH = 4;
constexpr int MROWS = BATCH * SEQ;   // 8192
constexpr int KDIM = 1024;

#define GLOAD_LDS16(g, l) __builtin_amdgcn_global_load_lds( \
    (const __attribute__((address_space(1))) void*)(g), \
    (__attribute__((address_space(3))) void*)(l), 16, 0, 0)

// ---------------- f32 -> bf16 conversion ----------------
__global__ void cvt_bf16(const float* __restrict__ src, bf16* __restrict__ dst, int n) {
    int i = (blockIdx.x * blockDim.x + threadIdx.x) * 8;
    if (i >= n) return;
    float4 f0 = *reinterpret_cast<const float4*>(src + i);
    float4 f1 = *reinterpret_cast<const float4*>(src + i + 4);
    bf16x8 o;
    o[0] = (bf16)f0.x; o[1] = (bf16)f0.y; o[2] = (bf16)f0.z; o[3] = (bf16)f0.w;
    o[4] = (bf16)f1.x; o[5] = (bf16)f1.y; o[6] = (bf16)f1.z; o[7] = (bf16)f1.w;
    *reinterpret_cast<bf16x8*>(dst + i) = o;
}

// ---------------- RoPE tables ----------------
__global__ void rope_tab(float* __restrict__ cosT, float* __restrict__ sinT) {
    int i = blockIdx.x * blockDim.x + threadIdx.x;  // [0, 2048*32)
    int p = i >> 5, k = i & 31;
    float inv = powf(10000.0f, -2.0f * (float)k / 64.0f);
    float ang = (float)p * inv;
    cosT[i] = cosf(ang);
    sinT[i] = sinf(ang);
}

// ---------------- QKV GEMM (C = X * W^T), RoPE fused, out bf16 [B,H,S,DK] ----------------
__global__ __launch_bounds__(256) void gemm_qkv(
    const bf16* __restrict__ Xb,
    const bf16* __restrict__ Wqb, const bf16* __restrict__ Wkb, const bf16* __restrict__ Wvb,
    bf16* __restrict__ Qb, bf16* __restrict__ Kb, bf16* __restrict__ Vb,
    const int* __restrict__ tokpos, const float* __restrict__ cosT, const float* __restrict__ sinT)
{
    __shared__ bf16 As[128 * 64];
    __shared__ bf16 Bs[128 * 64];

    const int which = blockIdx.z;
    const bf16* Bmat = which == 0 ? Wqb : (which == 1 ? Wkb : Wvb);
    bf16* Out = which == 0 ? Qb : (which == 1 ? Kb : Vb);

    const int m0 = blockIdx.x * 128;
    const int n0 = blockIdx.y * 128;
    const int t = threadIdx.x;
    const int w = t >> 6, l = t & 63;
    const int wr = w >> 1, wc = w & 1;
    const int lrow = l >> 3;          // 0..7
    const int lcol = (l & 7) * 8;     // bf16 col within BK
    const int lm = l & 15, lg = l >> 4;

    f32x4 acc[4][4] = {};

    for (int kt = 0; kt < KDIM; kt += 64) {
#pragma unroll
        for (int c = 0; c < 4; ++c) {
            int ci = c * 4 + w;            // 0..15
            int row = ci * 8 + lrow;       // 0..127
            const bf16* ga = Xb + (size_t)(m0 + row) * KDIM + kt + lcol;
            const bf16* gb = Bmat + (size_t)(n0 + row) * KDIM + kt + lcol;
            GLOAD_LDS16(ga, As + ci * 512);
            GLOAD_LDS16(gb, Bs + ci * 512);
        }
        __syncthreads();
#pragma unroll
        for (int kk = 0; kk < 2; ++kk) {
            bf16x8 af[4], bfr[4];
#pragma unroll
            for (int mi = 0; mi < 4; ++mi)
                af[mi] = *reinterpret_cast<const bf16x8*>(As + (wr * 64 + mi * 16 + lm) * 64 + kk * 32 + lg * 8);
#pragma unroll
            for (int ni = 0; ni < 4; ++ni)
                bfr[ni] = *reinterpret_cast<const bf16x8*>(Bs + (wc * 64 + ni * 16 + lm) * 64 + kk * 32 + lg * 8);
#pragma unroll
            for (int mi = 0; mi < 4; ++mi)
#pragma unroll
                for (int ni = 0; ni < 4; ++ni)
                    acc[mi][ni] = __builtin_amdgcn_mfma_f32_16x16x32_bf16(af[mi], bfr[ni], acc[mi][ni], 0, 0, 0);
        }
        __syncthreads();
    }

    // epilogue: RoPE (Q,K only) + scatter to [B,H,S,DK] bf16
#pragma unroll
    for (int ni = 0; ni < 4; ++ni) {
        int j = n0 + wc * 64 + ni * 16 + lm;   // global col in [0,1024)
        int h = j >> 6, d = j & 63;
        int k2 = d >> 1;
        bool even = (d & 1) == 0;
#pragma unroll
        for (int mi = 0; mi < 4; ++mi) {
#pragma unroll
            for (int r = 0; r < 4; ++r) {
                int rowg = m0 + wr * 64 + mi * 16 + lg * 4 + r;   // global row
                float v = acc[mi][ni][r];
                float outv;
                if (which < 2) {
                    int p = tokpos[rowg];
                    float cv = cosT[p * 32 + k2];
                    float sv = sinT[p * 32 + k2];
                    float u = __shfl_xor(v, 1);
                    outv = even ? (v * cv - u * sv) : (v * cv + u * sv);
                } else {
                    outv = v;
                }
                int bb = rowg >> 11, ss = rowg & 2047;
                size_t oidx = (((size_t)(bb * NH + h)) * SEQ + ss) * DK + d;
                Out[oidx] = (bf16)outv;
            }
        }
    }
}

// ---------------- V transpose [B,H,S,DK] -> [B,H,DK,S] ----------------
__global__ void vtrans(const bf16* __restrict__ Vb, bf16* __restrict__ Vt) {
    __shared__ ushortT tile[64][66];
    int bh = blockIdx.y, st = blockIdx.x;
    int t = threadIdx.x;
    int r = t >> 2, c4 = (t & 3) * 16;
    const ushortT* src = (const ushortT*)(Vb + ((size_t)bh * SEQ + st * 64 + r) * DK + c4);
    *reinterpret_cast<ushort8*>(&tile[r][c4]) = *reinterpret_cast<const ushort8*>(src);
    *reinterpret_cast<ushort8*>(&tile[r][c4 + 8]) = *reinterpret_cast<const ushort8*>(src + 8);
    __syncthreads();
    ushort8 o0, o1;
#pragma unroll
    for (int i = 0; i < 8; ++i) o0[i] = tile[c4 + i][r];
#pragma unroll
    for (int i = 0; i < 8; ++i) o1[i] = tile[c4 + 8 + i][r];
    ushortT* dst = (ushortT*)(Vt + ((size_t)bh * DK + r) * SEQ + st * 64 + c4);
    *reinterpret_cast<ushort8*>(dst) = o0;
    *reinterpret_cast<ushort8*>(dst + 8) = o1;
}

// ---------------- flash attention (causal), swapped-QK in-register softmax ----------------
// grid: (B*H, S/128); block 256 = 4 waves, each wave owns 32 q-rows, KV tile 64.
// S^T = mfma(K,Q): lane owns q-row lm; kv = c*16 + lg*4 + i.
// O^T = mfma(V^T, P^T): alpha/sum lane-local; output C[d=lg*4+i][q=lm].
constexpr float CL = 0.18033688011112042f;  // 0.125 * log2(e)

template<bool MASK>
DEV void attn_iter(int kv0, int qabs0, int lm, int lg,
                   const bf16* __restrict__ Kh, const bf16* __restrict__ Vh,
                   const bf16x8 qf[2][2],
                   f32x4 o[2][4], float lsum[2], float mrow[2])
{
    f32x4 s[2][4] = {};
#pragma unroll
    for (int c = 0; c < 4; ++c) {
        const bf16* kr = Kh + (size_t)(kv0 + c * 16 + lm) * DK + lg * 8;
        bf16x8 kf0 = *reinterpret_cast<const bf16x8*>(kr);
        bf16x8 kf1 = *reinterpret_cast<const bf16x8*>(kr + 32);
#pragma unroll
        for (int qi = 0; qi < 2; ++qi) {
            s[qi][c] = __builtin_amdgcn_mfma_f32_16x16x32_bf16(kf0, qf[qi][0], s[qi][c], 0, 0, 0);
            s[qi][c] = __builtin_amdgcn_mfma_f32_16x16x32_bf16(kf1, qf[qi][1], s[qi][c], 0, 0, 0);
        }
    }

    uintT w[2][4][2];   // [qi][c][t] packed bf16 pairs of P
#pragma unroll
    for (int qi = 0; qi < 2; ++qi) {
        const int qrow = qabs0 + qi * 16;
        if (MASK) {
#pragma unroll
            for (int c = 0; c < 4; ++c)
#pragma unroll
                for (int i = 0; i < 4; ++i)
                    if (kv0 + c * 16 + lg * 4 + i > qrow) s[qi][c][i] = -1e30f;
        }
        // lane-local row max over 16 values, then 2-shuffle cross-lg reduce
        f32x4 m01, m23;
#pragma unroll
        for (int i = 0; i < 4; ++i) {
            m01[i] = fmaxf(s[qi][0][i], s[qi][1][i]);
            m23[i] = fmaxf(s[qi][2][i], s[qi][3][i]);
        }
        float mx = fmaxf(fmaxf(fmaxf(m01[0], m01[1]), fmaxf(m01[2], m01[3])),
                         fmaxf(fmaxf(m23[0], m23[1]), fmaxf(m23[2], m23[3])));
        mx = fmaxf(mx, __shfl_xor(mx, 16));
        mx = fmaxf(mx, __shfl_xor(mx, 32));
        const float mnew = fmaxf(mrow[qi], mx);
        const float alpha = exp2f((mrow[qi] - mnew) * CL);
        mrow[qi] = mnew;
#pragma unroll
        for (int c = 0; c < 4; ++c)
#pragma unroll
            for (int i = 0; i < 4; ++i)
                s[qi][c][i] = exp2f((s[qi][c][i] - mnew) * CL);
        // lane-local partial sum (cross-lg reduced once at the end)
        f32x4 ps4;
#pragma unroll
        for (int i = 0; i < 4; ++i)
            ps4[i] = (s[qi][0][i] + s[qi][1][i]) + (s[qi][2][i] + s[qi][3][i]);
        const float ps = (ps4[0] + ps4[1]) + (ps4[2] + ps4[3]);
        lsum[qi] = lsum[qi] * alpha + ps;
#pragma unroll
        for (int dc = 0; dc < 4; ++dc)
#pragma unroll
            for (int i = 0; i < 4; ++i)
                o[qi][dc][i] *= alpha;
        // pack bf16 pairs
#pragma unroll
        for (int c = 0; c < 4; ++c)
#pragma unroll
            for (int t2 = 0; t2 < 2; ++t2) {
                uintT lo = (uintT)__builtin_bit_cast(ushortT, (bf16)s[qi][c][2 * t2]);
                uintT hi = (uintT)__builtin_bit_cast(ushortT, (bf16)s[qi][c][2 * t2 + 1]);
                w[qi][c][t2] = (hi << 16) | lo;
            }
    }

    // PV: O^T += V^T-frag x P^T-frag ; P^T B-frags built via bpermute pulls
    const int hi_half = lg >> 1;
#pragma unroll
    for (int s2 = 0; s2 < 2; ++s2) {
        bf16x8 vf[4];
#pragma unroll
        for (int dc = 0; dc < 4; ++dc)
            vf[dc] = *reinterpret_cast<const bf16x8*>(Vh + (size_t)(dc * 16 + lm) * SEQ + kv0 + s2 * 32 + lg * 8);
#pragma unroll
        for (int qi = 0; qi < 2; ++qi) {
            uint4v tw;
#pragma unroll
            for (int u = 0; u < 4; ++u) {
                const int src = lm + 16 * (2 * (lg & 1) + (u >> 1));
                uintT p0 = (uintT)__shfl((int)w[qi][2 * s2][u & 1], src);
                uintT p1 = (uintT)__shfl((int)w[qi][2 * s2 + 1][u & 1], src);
                tw[u] = hi_half ? p1 : p0;
            }
            bf16x8 pa = __builtin_bit_cast(bf16x8, tw);
#pragma unroll
            for (int dc = 0; dc < 4; ++dc)
                o[qi][dc] = __builtin_amdgcn_mfma_f32_16x16x32_bf16(vf[dc], pa, o[qi][dc], 0, 0, 0);
        }
    }
}

__global__ __launch_bounds__(256, 4) void attn(
    const bf16* __restrict__ Qb, const bf16* __restrict__ Kb, const bf16* __restrict__ Vt,
    bf16* __restrict__ Ab)
{
    const int bh = blockIdx.x;
    const int qt = (int)gridDim.y - 1 - (int)blockIdx.y;   // longest tiles launch first
    const int t = threadIdx.x, w = t >> 6, l = t & 63;
    const int lm = l & 15, lg = l >> 4;
    const int q0 = qt * 128 + w * 32;
    const bf16* Qh = Qb + (size_t)bh * SEQ * DK;
    const bf16* Kh = Kb + (size_t)bh * SEQ * DK;
    const bf16* Vh = Vt + (size_t)bh * DK * SEQ;

    bf16x8 qf[2][2];
#pragma unroll
    for (int qi = 0; qi < 2; ++qi)
#pragma unroll
        for (int kk = 0; kk < 2; ++kk)
            qf[qi][kk] = *reinterpret_cast<const bf16x8*>(Qh + (size_t)(q0 + qi * 16 + lm) * DK + kk * 32 + lg * 8);

    f32x4 o[2][4] = {};
    float lsum[2] = {0.0f, 0.0f};
    float mrow[2] = {-1e30f, -1e30f};
    const int qabs0 = q0 + lm;

    const int nfull = q0 >> 6;
    int kv0 = 0;
    for (int tt = 0; tt < nfull; ++tt, kv0 += 64)
        attn_iter<false>(kv0, qabs0, lm, lg, Kh, Vh, qf, o, lsum, mrow);
    attn_iter<true>(kv0, qabs0, lm, lg, Kh, Vh, qf, o, lsum, mrow);

    const int b = bh >> 4, h = bh & 15;
#pragma unroll
    for (int qi = 0; qi < 2; ++qi) {
        float rs = lsum[qi];
        rs += __shfl_xor(rs, 16);
        rs += __shfl_xor(rs, 32);
        const float rinv = 1.0f / rs;
        const int q = q0 + qi * 16 + lm;
        const size_t rowbase = ((size_t)(b * SEQ + q)) * DMODEL + h * 64;
#pragma unroll
        for (int dc = 0; dc < 4; ++dc) {
            bf16x4 v4;
#pragma unroll
            for (int i = 0; i < 4; ++i) v4[i] = (bf16)(o[qi][dc][i] * rinv);
            *reinterpret_cast<bf16x4*>(Ab + rowbase + dc * 16 + lg * 4) = v4;
        }
    }
}

// ---------------- output GEMM (d_out = Ab * Wo^T), f32 out ----------------
__global__ __launch_bounds__(256) void gemm_out(
    const bf16* __restrict__ Ab, const bf16* __restrict__ Wob, float* __restrict__ Out)
{
    __shared__ bf16 As[128 * 64];
    __shared__ bf16 Bs[128 * 64];

    const int m0 = blockIdx.x * 128;
    const int n0 = blockIdx.y * 128;
    const int t = threadIdx.x;
    const int w = t >> 6, l = t & 63;
    const int wr = w >> 1, wc = w & 1;
    const int lrow = l >> 3;
    const int lcol = (l & 7) * 8;
    const int lm = l & 15, lg = l >> 4;

    f32x4 acc[4][4] = {};

    for (int kt = 0; kt < KDIM; kt += 64) {
#pragma unroll
        for (int c = 0; c < 4; ++c) {
            int ci = c * 4 + w;
            int row = ci * 8 + lrow;
            const bf16* ga = Ab + (size_t)(m0 + row) * KDIM + kt + lcol;
            const bf16* gb = Wob + (size_t)(n0 + row) * KDIM + kt + lcol;
            GLOAD_LDS16(ga, As + ci * 512);
            GLOAD_LDS16(gb, Bs + ci * 512);
        }
        __syncthreads();
#pragma unroll
        for (int kk = 0; kk < 2; ++kk) {
            bf16x8 af[4], bfr[4];
#pragma unroll
            for (int mi = 0; mi < 4; ++mi)
                af[mi] = *reinterpret_cast<const bf16x8*>(As + (wr * 64 + mi * 16 + lm) * 64 + kk * 32 + lg * 8);
#pragma unroll
            for (int ni = 0; ni < 4; ++ni)
                bfr[ni] = *reinterpret_cast<const bf16x8*>(Bs + (wc * 64 + ni * 16 + lm) * 64 + kk * 32 + lg * 8);
#pragma unroll
            for (int mi = 0; mi < 4; ++mi)
#pragma unroll
                for (int ni = 0; ni < 4; ++ni)
                    acc[mi][ni] = __builtin_amdgcn_mfma_f32_16x16x32_bf16(af[mi], bfr[ni], acc[mi][ni], 0, 0, 0);
        }
        __syncthreads();
    }

#pragma unroll
    for (int ni = 0; ni < 4; ++ni) {
        int j = n0 + wc * 64 + ni * 16 + lm;
#pragma unroll
        for (int mi = 0; mi < 4; ++mi) {
#pragma unroll
            for (int r = 0; r < 4; ++r) {
                int rowg = m0 + wr * 64 + mi * 16 + lg * 4 + r;
                Out[(size_t)rowg * DMODEL + j] = acc[mi][ni][r];
            }
        }
    }
}

// ---------------- launch ----------------
extern "C" void kernel_launch(void* const* d_in, const int* in_sizes, int n_in,
                              void* d_out, int out_size, void* d_ws, size_t ws_size,
                              hipStream_t stream) {
    const float* X  = (const float*)d_in[0];
    const int* tokpos = (const int*)d_in[1];
    const float* Wq = (const float*)d_in[2];
    const float* Wk = (const float*)d_in[3];
    const float* Wv = (const float*)d_in[4];
    const float* Wo = (const float*)d_in[5];

    char* ws = (char*)d_ws;
    bf16* Xb  = (bf16*)(ws + 0);            // 16 MB
    bf16* Wqb = (bf16*)(ws + 16777216);     // 2 MB
    bf16* Wkb = (bf16*)(ws + 18874368);
    bf16* Wvb = (bf16*)(ws + 20971520);
    bf16* Wob = (bf16*)(ws + 23068672);
    float* cosT = (float*)(ws + 25165824);  // 256 KB
    float* sinT = (float*)(ws + 25427968);
    bf16* Qb = (bf16*)(ws + 25690112);      // 16 MB
    bf16* Kb = (bf16*)(ws + 42467328);
    bf16* Vb = (bf16*)(ws + 59244544);
    bf16* Vt = (bf16*)(ws + 76021760);
    bf16* Ab = (bf16*)(ws + 92798976);      // ends at 109,576,192

    cvt_bf16<<<4096, 256, 0, stream>>>(X, Xb, MROWS * DMODEL);
    cvt_bf16<<<512, 256, 0, stream>>>(Wq, Wqb, DMODEL * DMODEL);
    cvt_bf16<<<512, 256, 0, stream>>>(Wk, Wkb, DMODEL * DMODEL);
    cvt_bf16<<<512, 256, 0, stream>>>(Wv, Wvb, DMODEL * DMODEL);
    cvt_bf16<<<512, 256, 0, stream>>>(Wo, Wob, DMODEL * DMODEL);
    rope_tab<<<256, 256, 0, stream>>>(cosT, sinT);

    gemm_qkv<<<dim3(MROWS / 128, DMODEL / 128, 3), 256, 0, stream>>>(
        Xb, Wqb, Wkb, Wvb, Qb, Kb, Vb, tokpos, cosT, sinT);

    vtrans<<<dim3(SEQ / 64, BATCH * NH), 256, 0, stream>>>(Vb, Vt);

    attn<<<dim3(BATCH * NH, SEQ / 128), 256, 0, stream>>>(Qb, Kb, Vt, Ab);

    gemm_out<<<dim3(MROWS / 128, DMODEL / 128), 256, 0, stream>>>(Ab, Wob, (float*)d_out);
}